// Round 3
// 2790.584 us; speedup vs baseline: 1.0100x; 1.0100x over previous
//
#include <hip/hip_runtime.h>
#include <hip/hip_bf16.h>
#include <math.h>

#define PAD 2

typedef __attribute__((ext_vector_type(8))) short s8v;    // 8 bf16 = 4 VGPRs
typedef __attribute__((ext_vector_type(4))) float f4v;    // 4 fp32 acc

__device__ __forceinline__ f4v mfma16(s8v a, s8v b, f4v c){
    return __builtin_amdgcn_mfma_f32_16x16x32_bf16(a, b, c, 0, 0, 0);
}

__device__ __forceinline__ void gl_lds16(const void* g, void* l){
    __builtin_amdgcn_global_load_lds(
        (const __attribute__((address_space(1))) void*)g,
        (__attribute__((address_space(3))) void*)l, 16, 0, 0);
}

__device__ __forceinline__ unsigned short f2bf(float f){
    unsigned u = __float_as_uint(f);
    unsigned r = u + 0x7FFFu + ((u >> 16) & 1u);
    return (unsigned short)(r >> 16);
}

// ---- ordered-uint encoding for float atomicMax ----
__device__ __forceinline__ unsigned f2o(float f){
    unsigned b = __float_as_uint(f);
    return (b & 0x80000000u) ? ~b : (b | 0x80000000u);
}
__device__ __forceinline__ float o2f(unsigned u){
    return __uint_as_float((u & 0x80000000u) ? (u & 0x7fffffffu) : ~u);
}

// ============================================================
// corr: thread = (pixel, k). grid = (25, 4HW/256) — k fastest so the
// 25 blocks of one pixel tile are dispatch-adjacent (L2 locality).
// ============================================================
__global__ void corr_kernel(const float* __restrict__ key, const float* __restrict__ frame,
                            float* __restrict__ corr, unsigned* __restrict__ gmax,
                            int C, int H, int W, int logHW, int logW){
    const int HW = H * W;
    const int k = blockIdx.x;
    const int di = k / 5 - PAD, dj = (k % 5) - PAD;
    const int p = blockIdx.y * 256 + threadIdx.x;
    const int b = p >> logHW;
    const int rem = p & (HW - 1);
    const int y = rem >> logW, x = rem & (W - 1);
    const bool v = ((unsigned)(y + di) < (unsigned)H) && ((unsigned)(x + dj) < (unsigned)W);
    const int off = v ? di * W + dj : 0;

    const float* kp = key   + (((size_t)b * C) << logHW) + rem;
    const float* fp = frame + (((size_t)b * C) << logHW) + rem + off;

    float acc = 0.f;
    #pragma unroll 4
    for (int c = 0; c < C; c++)
        acc += kp[c * HW] * fp[c * HW];
    acc = v ? acc : 0.f;

    corr[(((size_t)b * 25 + k) << logHW) + rem] = acc;

    float m = acc;
    #pragma unroll
    for (int o = 32; o > 0; o >>= 1) m = fmaxf(m, __shfl_down(m, o));
    if ((threadIdx.x & 63) == 0) atomicMax(gmax, f2o(m));
}

// ============================================================
// att: softmax over the 25 offsets, in-place on corr buffer.
// ============================================================
__global__ void att_kernel(float* __restrict__ corr, const unsigned* __restrict__ gmax,
                           int logHW){
    const int p = blockIdx.x * 256 + threadIdx.x;
    const int b = p >> logHW;
    const int rem = p & ((1 << logHW) - 1);
    float* cp = corr + (((size_t)b * 25) << logHW) + rem;
    const float scale = 20.f / o2f(*gmax);

    float z[25]; float m = -INFINITY;
    #pragma unroll
    for (int k = 0; k < 25; k++){
        z[k] = cp[k << logHW] * scale;
        m = fmaxf(m, z[k]);
    }
    float s = 0.f;
    #pragma unroll
    for (int k = 0; k < 25; k++){ z[k] = expf(z[k] - m); s += z[k]; }
    const float inv = 1.f / s;
    #pragma unroll
    for (int k = 0; k < 25; k++) cp[k << logHW] = z[k] * inv;
}

// ============================================================
// warp_gather: thread = (c, pixel). grid = (4HW/256, C).
// ============================================================
__global__ void warp_gather(const float* __restrict__ frame, const float* __restrict__ att,
                            float* __restrict__ newf,
                            int C, int H, int W, int logHW, int logW){
    const int c = blockIdx.y;
    const int p = blockIdx.x * 256 + threadIdx.x;
    const int b = p >> logHW;
    const int rem = p & ((1 << logHW) - 1);
    const int y = rem >> logW, x = rem & (W - 1);

    const float* ap = att   + (((size_t)b * 25) << logHW) + rem;
    const float* fp = frame + (((size_t)b * C + c) << logHW) + rem;

    float acc = 0.f;
    #pragma unroll
    for (int i = 0; i < 5; i++){
        #pragma unroll
        for (int j = 0; j < 5; j++){
            const int k = i * 5 + j;
            const bool v = ((unsigned)(y + i - PAD) < (unsigned)H) &&
                           ((unsigned)(x + j - PAD) < (unsigned)W);
            const int off = v ? (i - PAD) * W + (j - PAD) : 0;
            acc += ap[k << logHW] * (fp[off] * (v ? 1.f : 0.f));
        }
    }
    newf[(((size_t)b * C + c) << logHW) + rem] = acc;
}

// ============================================================
// gate (unchanged, fp32)
// ============================================================
__global__ void gate_kernel(const float* __restrict__ key, const float* __restrict__ newf,
                            const float* __restrict__ Wg, const float* __restrict__ bg,
                            float* __restrict__ g, int C, int H, int W){
    const int HW = H * W;
    int tx = threadIdx.x, ty = threadIdx.y;
    int p = blockIdx.x * 64 + tx;
    int b = p / HW; int rem = p - b * HW; int y = rem / W; int x = rem - y * W;

    int half = C >> 1;
    int u0 = ty * half;
    const float* in = (u0 < C) ? (key  + ((size_t)b * C + u0) * HW)
                               : (newf + ((size_t)b * C + (u0 - C)) * HW);

    int off[9]; float msk[9];
    #pragma unroll
    for (int t = 0; t < 9; t++){
        int dy = t / 3 - 1, dx = t % 3 - 1;
        int yy = y + dy, xx = x + dx;
        bool v = (yy >= 0) && (yy < H) && (xx >= 0) && (xx < W);
        off[t] = v ? dy * W + dx : 0;
        msk[t] = v ? 1.f : 0.f;
    }

    float acc0 = 0.f, acc1 = 0.f;
    for (int uu = 0; uu < half; uu++){
        int u = u0 + uu;
        const float* ip = in + (size_t)uu * HW + rem;
        const float* w0 = Wg + (size_t)u * 9;
        const float* w1 = Wg + ((size_t)2 * C + u) * 9;
        #pragma unroll
        for (int t = 0; t < 9; t++){
            float v = ip[off[t]] * msk[t];
            acc0 += v * w0[t];
            acc1 += v * w1[t];
        }
    }

    __shared__ float sg[2][4][64];
    sg[0][ty][tx] = acc0; sg[1][ty][tx] = acc1;
    __syncthreads();
    if (ty == 0){
        float z0 = sg[0][0][tx] + sg[0][1][tx] + sg[0][2][tx] + sg[0][3][tx] + bg[0];
        float z1 = sg[1][0][tx] + sg[1][1][tx] + sg[1][2][tx] + sg[1][3][tx] + bg[1];
        g[((size_t)b * 2 + 0) * HW + rem] = 1.f / (1.f + expf(-z0));
        g[((size_t)b * 2 + 1) * HW + rem] = 1.f / (1.f + expf(-z1));
    }
}

// ============================================================
// prep_gin: NCHW fp32 (key,new) * gate -> NHWC bf16 gin[b*HW][2C]
// ============================================================
__global__ void prep_gin(const float* __restrict__ key, const float* __restrict__ newf,
                         const float* __restrict__ g, unsigned short* __restrict__ gin,
                         int C, int HW){
    __shared__ unsigned short tile[64][65];
    int tid = threadIdx.x;
    int pt0 = blockIdx.x * 64;
    int u0  = blockIdx.y * 64;
    int b   = pt0 / HW;
    int rem0 = pt0 - b * HW;
    const float* gb = g + (size_t)(b * 2) * HW;

    #pragma unroll
    for (int it = 0; it < 16; it++){
        int idx = it * 256 + tid;
        int ur = idx >> 6, pc = idx & 63;
        int u = u0 + ur; int rem = rem0 + pc;
        const float* src; int sel;
        if (u < C){ src = key  + ((size_t)b * C + u) * HW;       sel = 0; }
        else      { src = newf + ((size_t)b * C + (u - C)) * HW; sel = 1; }
        float v = src[rem] * gb[(size_t)sel * HW + rem];
        tile[ur][pc] = f2bf(v);
    }
    __syncthreads();
    unsigned short* go = gin + (size_t)pt0 * (2 * C) + u0;
    #pragma unroll
    for (int it = 0; it < 16; it++){
        int idx = it * 256 + tid;
        int pr = idx >> 6, uc = idx & 63;
        go[(size_t)pr * (2 * C) + uc] = tile[uc][pr];
    }
}

// ============================================================
// prep_w: W[co][ci][t] fp32 -> Wt[co][t*Cin+ci] bf16
// ============================================================
__global__ void prep_w(const float* __restrict__ W, unsigned short* __restrict__ Wt,
                       int Cin){
    int ci = blockIdx.y * 256 + threadIdx.x;
    int bx = blockIdx.x;
    int co = bx / 9, t = bx - co * 9;
    Wt[(size_t)bx * Cin + ci] = f2bf(W[((size_t)co * Cin + ci) * 9 + t]);
}

// ============================================================
// conv_mfma v4b: deep software pipeline (T3+T4+T5).
// 5 LDS buffers, loads issued 3 K-steps ahead, raw s_barrier +
// counted s_waitcnt vmcnt(N) (never 0 in steady state) so
// global_load_lds stays in flight across barriers — v3's
// __syncthreads() forced a vmcnt(0) drain every K-step, exposing
// full L2/L3 latency (MfmaUtil 12%). sched_barrier(0) pins the
// scheduler right after each hand-written waitcnt (rule #18).
// s_setprio(1) around the MFMA cluster. LDS 60KB/block (BN=128)
// -> 2 blocks/CU. Wave grid 2x2; XOR-swizzled LDS (0 conflicts).
// ============================================================
template<int BN, int EPI>
__global__ __launch_bounds__(256, 2)
void conv_mfma(const unsigned short* __restrict__ gin,
               const unsigned short* __restrict__ Wt,
               const float* __restrict__ bias,
               unsigned short* __restrict__ obf, int ostride,
               float* __restrict__ of32,
               const void* __restrict__ zp,
               int Cin, int Cout, int H, int W, int logHW, int logW)
{
    constexpr int BM = 64;
    constexpr int BNh = BN / 2;
    constexpr int NJ = BN / 32;
    constexpr int NBUF = 5;
    __shared__ __align__(16) unsigned short sA[NBUF][BM * 32];
    __shared__ __align__(16) unsigned short sB[NBUF][BN * 32];

    const int tid = threadIdx.x;
    const int lane = tid & 63;
    const int wv = tid >> 6;
    const int wm = wv >> 1, wn = wv & 1;
    const int ln = lane & 15, q = lane >> 4;

    const int p0 = blockIdx.x * BM;
    const int b  = p0 >> logHW;
    const int rem0 = p0 - (b << logHW);

    // staging: row = tid>>2 (0..63); swizzled global chunk
    const int rowA0 = tid >> 2;
    const int gc8 = ((tid & 3) ^ ((tid >> 3) & 3)) * 8;    // element offset
    const int remA0 = rem0 + rowA0;
    const int yA0 = remA0 >> logW, xA0 = remA0 & (W - 1);
    const size_t pbase = ((size_t)b << logHW);

    const int nt0 = blockIdx.y * BN;
    const size_t Ktot = (size_t)9 * Cin;
    const unsigned short* wB0 = Wt + (size_t)(nt0 + rowA0) * Ktot + gc8;

    f4v acc[2][NJ];
    #pragma unroll
    for (int i = 0; i < 2; i++)
        #pragma unroll
        for (int j = 0; j < NJ; j++){ f4v z = {0.f, 0.f, 0.f, 0.f}; acc[i][j] = z; }

    const int cblocks = Cin >> 5;
    const int total = 9 * cblocks;

    // staging-cursor state (for the NEXT K-block to stage)
    int sbuf = 0;                                  // LDS buffer 0..NBUF-1
    int scb = 0;                                   // k-chunk within tap
    int st  = 0;                                   // tap index
    bool sv = (yA0 > 0) && (xA0 > 0);              // tap 0: dy=-1,dx=-1
    const unsigned short* sa  = gin + (pbase + remA0 + (-W - 1)) * Cin + gc8;
    const unsigned short* swb = wB0;               // +32 per staged K-block

    auto do_stage = [&](){
        gl_lds16(sv ? (const void*)(sa + scb * 32) : zp, (char*)sA[sbuf] + wv * 1024);
        char* dB = (char*)sB[sbuf];
        gl_lds16((const void*)swb, dB + wv * 1024);
        if constexpr (BN == 128)
            gl_lds16((const void*)(swb + (size_t)64 * Ktot), dB + 4096 + wv * 1024);
        swb += 32;
        sbuf = (sbuf == NBUF - 1) ? 0 : sbuf + 1;
        if (++scb == cblocks){
            scb = 0; ++st;
            const int dy = st / 3 - 1, dx = st - (st / 3) * 3 - 1;
            sv = ((unsigned)(yA0 + dy) < (unsigned)H) && ((unsigned)(xA0 + dx) < (unsigned)W);
            sa = gin + (pbase + remA0 + dy * W + dx) * Cin + gc8;
        }
    };

    // prologue: 3 K-blocks in flight (total = 9*cblocks >= 144 always)
    do_stage(); do_stage(); do_stage();

    const int rchunk = (q ^ ((ln >> 1) & 3)) * 8;   // swizzled read offset
    int cbuf = 0;
    for (int kb = 0; kb < total; kb++){
        // wait until K-block kb's loads landed; keep kb+1/kb+2 in flight.
        // loads-per-stage per wave: BN==128 -> 3, BN==64 -> 2.
        if (kb + 2 < total){
            if constexpr (BN == 128) asm volatile("s_waitcnt vmcnt(6)" ::: "memory");
            else                     asm volatile("s_waitcnt vmcnt(4)" ::: "memory");
        } else if (kb + 1 < total){
            if constexpr (BN == 128) asm volatile("s_waitcnt vmcnt(3)" ::: "memory");
            else                     asm volatile("s_waitcnt vmcnt(2)" ::: "memory");
        } else {
            asm volatile("s_waitcnt vmcnt(0)" ::: "memory");
        }
        __builtin_amdgcn_sched_barrier(0);
        __builtin_amdgcn_s_barrier();
        __builtin_amdgcn_sched_barrier(0);
        // WAR-safe: buf (kb+3)%5 was read at iter kb-2; every wave's
        // lgkm-waits before its iter kb-1 MFMAs drained those ds_reads
        // before it could reach the barrier above.
        if (kb + 3 < total) do_stage();

        const unsigned short* A = sA[cbuf];
        const unsigned short* B = sB[cbuf];
        cbuf = (cbuf == NBUF - 1) ? 0 : cbuf + 1;

        s8v af[2];
        #pragma unroll
        for (int i = 0; i < 2; i++)
            af[i] = *(const s8v*)(A + (wm * 32 + i * 16 + ln) * 32 + rchunk);
        __builtin_amdgcn_s_setprio(1);
        #pragma unroll
        for (int j = 0; j < NJ; j++){
            s8v bfr = *(const s8v*)(B + (wn * BNh + j * 16 + ln) * 32 + rchunk);
            #pragma unroll
            for (int i = 0; i < 2; i++)
                acc[i][j] = mfma16(af[i], bfr, acc[i][j]);
        }
        __builtin_amdgcn_s_setprio(0);
    }

    // epilogue: D rows m = q*4+r (pixels), cols n = ln (cout)
    #pragma unroll
    for (int i = 0; i < 2; i++){
        const int m0 = wm * 32 + i * 16 + q * 4;
        const int p = p0 + m0;
        #pragma unroll
        for (int j = 0; j < NJ; j++){
            const int n = nt0 + wn * BNh + j * 16 + ln;
            const float bv = bias[n];
            if (EPI == 0){
                #pragma unroll
                for (int r = 0; r < 4; r++){
                    float v = fmaxf(acc[i][j][r] + bv, 0.f);
                    obf[(size_t)(p + r) * ostride + n] = f2bf(v);
                }
            } else {
                f4v o;
                #pragma unroll
                for (int r = 0; r < 4; r++) o[r] = fmaxf(acc[i][j][r] + bv, 0.f);
                const int rem = rem0 + m0;
                *(f4v*)(of32 + (((size_t)b * Cout + n) << logHW) + rem) = o;
            }
        }
    }
}

// ============================================================
extern "C" void kernel_launch(void* const* d_in, const int* in_sizes, int n_in,
                              void* d_out, int out_size, void* d_ws, size_t ws_size,
                              hipStream_t stream){
    (void)in_sizes; (void)n_in; (void)out_size; (void)ws_size;

    const float* X[4][2];
    for (int s = 0; s < 4; s++)
        for (int l = 0; l < 2; l++)
            X[s][l] = (const float*)d_in[s * 2 + l];
    const float* Wg[2] = { (const float*)d_in[8],  (const float*)d_in[14] };
    const float* bg[2] = { (const float*)d_in[9],  (const float*)d_in[15] };
    const float* Wd[2] = { (const float*)d_in[10], (const float*)d_in[16] };
    const float* bd[2] = { (const float*)d_in[11], (const float*)d_in[17] };
    const float* Wc[2] = { (const float*)d_in[12], (const float*)d_in[18] };
    const float* bc[2] = { (const float*)d_in[13], (const float*)d_in[19] };
    float* out = (float*)d_out;

    char* ws = (char*)d_ws;
    unsigned* gmax = (unsigned*)ws;
    const void* zp = (const void*)(ws + 1024);
    float* corrbuf = (float*)(ws + 4096);
    float* newbuf  = (float*)(ws + 4096 + 1638400);
    unsigned short* wtbuf = (unsigned short*)newbuf;   // alias, disjoint lifetime
    float* gbuf    = (float*)(ws + 4096 + 1638400 + 16777216);
    unsigned short* ginbuf = (unsigned short*)(ws + 4096 + 1638400 + 16777216 + 131072);
    unsigned short* totbuf = (unsigned short*)(ws + 4096 + 1638400 + 16777216 + 131072 + 16777216);

    hipMemsetAsync(ws, 0, 4096, stream);

    const int Cs[2] = {256, 512};
    const int Hs[2] = {64, 32};
    const int logWs[2] = {6, 5};
    const int logHWs[2] = {12, 10};
    const size_t outOff[2] = {0, (size_t)4 * 256 * 4096};

    for (int l = 0; l < 2; l++){
        const int C = Cs[l], H = Hs[l], W = Hs[l], HW = H * W;
        const int logW = logWs[l], logHW = logHWs[l];
        const float* key = X[3][l];
        const int pblk = 4 * HW / 256;
        const dim3 gblk(64, 4);
        const int Mt = 4 * HW / 64;            // BM=64 tiles

        for (int s = 0; s < 3; s++){
            const float* fr = X[s][l];
            unsigned* slot = gmax + (l * 3 + s);
            corr_kernel<<<dim3(25, pblk), 256, 0, stream>>>(
                key, fr, corrbuf, slot, C, H, W, logHW, logW);
            att_kernel<<<pblk, 256, 0, stream>>>(corrbuf, slot, logHW);
            warp_gather<<<dim3(pblk, C), 256, 0, stream>>>(
                fr, corrbuf, newbuf, C, H, W, logHW, logW);
            gate_kernel<<<4 * HW / 64, gblk, 0, stream>>>(
                key, newbuf, Wg[l] + (size_t)s * 2 * (2 * C) * 9,
                bg[l] + (size_t)s * 2, gbuf, C, H, W);
            prep_gin<<<dim3(4 * HW / 64, 2 * C / 64), 256, 0, stream>>>(
                key, newbuf, gbuf, ginbuf, C, HW);
            prep_w<<<dim3(C * 9, 2 * C / 256), 256, 0, stream>>>(
                Wd[l] + (size_t)s * C * 2 * C * 9, wtbuf, 2 * C);
            if (l == 0)
                conv_mfma<128, 0><<<dim3(Mt, C / 128), 256, 0, stream>>>(
                    ginbuf, wtbuf, bd[l] + s * C, totbuf + s * C, 3 * C,
                    nullptr, zp, 2 * C, C, H, W, logHW, logW);
            else
                conv_mfma<64, 0><<<dim3(Mt, C / 64), 256, 0, stream>>>(
                    ginbuf, wtbuf, bd[l] + s * C, totbuf + s * C, 3 * C,
                    nullptr, zp, 2 * C, C, H, W, logHW, logW);
        }
        prep_w<<<dim3(C * 9, 3 * C / 256), 256, 0, stream>>>(Wc[l], wtbuf, 3 * C);
        if (l == 0)
            conv_mfma<128, 1><<<dim3(Mt, 2), 256, 0, stream>>>(
                totbuf, wtbuf, bc[l], nullptr, 0,
                out + outOff[l], zp, 3 * C, C, H, W, logHW, logW);
        else
            conv_mfma<64, 1><<<dim3(Mt, 8), 256, 0, stream>>>(
                totbuf, wtbuf, bc[l], nullptr, 0,
                out + outOff[l], zp, 3 * C, C, H, W, logHW, logW);
    }
}

// Round 5
// 2107.783 us; speedup vs baseline: 1.3372x; 1.3239x over previous
//
#include <hip/hip_runtime.h>
#include <hip/hip_bf16.h>
#include <math.h>

#define PAD 2

typedef __attribute__((ext_vector_type(8))) short s8v;    // 8 bf16 = 4 VGPRs
typedef __attribute__((ext_vector_type(4))) float f4v;    // 4 fp32 acc

__device__ __forceinline__ f4v mfma16(s8v a, s8v b, f4v c){
    return __builtin_amdgcn_mfma_f32_16x16x32_bf16(a, b, c, 0, 0, 0);
}

__device__ __forceinline__ void gl_lds16(const void* g, void* l){
    __builtin_amdgcn_global_load_lds(
        (const __attribute__((address_space(1))) void*)g,
        (__attribute__((address_space(3))) void*)l, 16, 0, 0);
}

__device__ __forceinline__ unsigned short f2bf(float f){
    unsigned u = __float_as_uint(f);
    unsigned r = u + 0x7FFFu + ((u >> 16) & 1u);
    return (unsigned short)(r >> 16);
}

// ---- ordered-uint encoding for float atomicMax ----
__device__ __forceinline__ unsigned f2o(float f){
    unsigned b = __float_as_uint(f);
    return (b & 0x80000000u) ? ~b : (b | 0x80000000u);
}
__device__ __forceinline__ float o2f(unsigned u){
    return __uint_as_float((u & 0x80000000u) ? (u & 0x7fffffffu) : ~u);
}

__device__ __forceinline__ float bperm(int adr, float v){
    return __uint_as_float((unsigned)__builtin_amdgcn_ds_bpermute(adr, (int)__float_as_uint(v)));
}

// ============================================================
// corr v2: wave = one 64-px row-band; per channel: 1 key load +
// 5 coalesced frame-row loads; dx shifts via ds_bpermute (lane±1,±2);
// masks precomputed. 4 waves/block = 4 c-chunks, LDS-combined;
// grid.y = extra c-split, combined via fp32 atomicAdd into the
// pre-zeroed corr buffer. Replaces the 25×-refetch structure
// (~840 MB L2 traffic/launch -> ~100 MB).
// ============================================================
__global__ __launch_bounds__(256)
void corr_v2(const float* __restrict__ key, const float* __restrict__ frame,
             float* __restrict__ corr,
             int C, int CW, int H, int W, int logHW, int logW){
    const int tid = threadIdx.x, lane = tid & 63, wv = tid >> 6;
    const int HW = 1 << logHW;
    const int p0 = blockIdx.x * 64;
    const int b  = p0 >> logHW;
    const int remL = (p0 & (HW - 1)) + lane;
    const int y = remL >> logW, x = remL & (W - 1);

    float m[25];
    #pragma unroll
    for (int t = 0; t < 25; t++){
        const int dy = t / 5 - 2, dx = t % 5 - 2;
        m[t] = (((unsigned)(y + dy) < (unsigned)H) &&
                ((unsigned)(x + dx) < (unsigned)W)) ? 1.f : 0.f;
    }
    int adr[4];
    const int dxs[4] = {-2, -1, 1, 2};
    #pragma unroll
    for (int i = 0; i < 4; i++) adr[i] = ((lane + dxs[i]) & 63) << 2;

    int roff[5];
    #pragma unroll
    for (int r = 0; r < 5; r++){
        const int dy = r - 2;
        roff[r] = ((unsigned)(y + dy) < (unsigned)H) ? dy * W : 0;
    }

    const int c0 = (blockIdx.y * 4 + wv) * CW;
    const float* kp = key   + (((size_t)b * C + c0) << logHW) + remL;
    const float* fp = frame + (((size_t)b * C + c0) << logHW) + remL;

    float acc[25];
    #pragma unroll
    for (int t = 0; t < 25; t++) acc[t] = 0.f;

    for (int ci = 0; ci < CW; ci++){
        const float k = kp[0];
        float f[5];
        #pragma unroll
        for (int r = 0; r < 5; r++) f[r] = fp[roff[r]];
        #pragma unroll
        for (int r = 0; r < 5; r++){
            float v[5];
            v[0] = bperm(adr[0], f[r]);
            v[1] = bperm(adr[1], f[r]);
            v[2] = f[r];
            v[3] = bperm(adr[2], f[r]);
            v[4] = bperm(adr[3], f[r]);
            #pragma unroll
            for (int j = 0; j < 5; j++)
                acc[r * 5 + j] += k * (v[j] * m[r * 5 + j]);
        }
        kp += HW; fp += HW;
    }

    __shared__ float sacc[4][25][64];
    #pragma unroll
    for (int t = 0; t < 25; t++) sacc[wv][t][lane] = acc[t];
    __syncthreads();
    #pragma unroll
    for (int tg = 0; tg < 7; tg++){
        const int t = wv + tg * 4;
        if (t < 25){
            const float s = sacc[0][t][lane] + sacc[1][t][lane] +
                            sacc[2][t][lane] + sacc[3][t][lane];
            atomicAdd(corr + (((size_t)b * 25 + t) << logHW) + remL, s);
        }
    }
}

// ============================================================
// global max over the summed corr buffer (runs after corr_v2).
// ============================================================
__global__ void max_kernel(const float* __restrict__ corr, unsigned* __restrict__ gmax){
    float v = corr[(size_t)blockIdx.x * 256 + threadIdx.x];
    #pragma unroll
    for (int o = 32; o > 0; o >>= 1) v = fmaxf(v, __shfl_down(v, o));
    if ((threadIdx.x & 63) == 0) atomicMax(gmax, f2o(v));
}

// ============================================================
// att: softmax over the 25 offsets, in-place on corr buffer.
// ============================================================
__global__ void att_kernel(float* __restrict__ corr, const unsigned* __restrict__ gmax,
                           int logHW){
    const int p = blockIdx.x * 256 + threadIdx.x;
    const int b = p >> logHW;
    const int rem = p & ((1 << logHW) - 1);
    float* cp = corr + (((size_t)b * 25) << logHW) + rem;
    const float scale = 20.f / o2f(*gmax);

    float z[25]; float m = -INFINITY;
    #pragma unroll
    for (int k = 0; k < 25; k++){
        z[k] = cp[k << logHW] * scale;
        m = fmaxf(m, z[k]);
    }
    float s = 0.f;
    #pragma unroll
    for (int k = 0; k < 25; k++){ z[k] = expf(z[k] - m); s += z[k]; }
    const float inv = 1.f / s;
    #pragma unroll
    for (int k = 0; k < 25; k++) cp[k << logHW] = z[k] * inv;
}

// ============================================================
// warp v2: same row-band/bpermute pattern as corr_v2. att (25 vals,
// masks folded in) lives in registers across the whole c-loop;
// per channel: 5 row loads + 20 bpermute + 25 FMA + 1 store.
// Output per (c,px) exclusive -> plain stores, no atomics.
// ============================================================
__global__ __launch_bounds__(256)
void warp_v2(const float* __restrict__ frame, const float* __restrict__ att,
             float* __restrict__ newf,
             int C, int CW, int H, int W, int logHW, int logW){
    const int tid = threadIdx.x, lane = tid & 63, wv = tid >> 6;
    const int HW = 1 << logHW;
    const int p0 = blockIdx.x * 64;
    const int b  = p0 >> logHW;
    const int remL = (p0 & (HW - 1)) + lane;
    const int y = remL >> logW, x = remL & (W - 1);

    int adr[4];
    const int dxs[4] = {-2, -1, 1, 2};
    #pragma unroll
    for (int i = 0; i < 4; i++) adr[i] = ((lane + dxs[i]) & 63) << 2;

    int roff[5];
    #pragma unroll
    for (int r = 0; r < 5; r++){
        const int dy = r - 2;
        roff[r] = ((unsigned)(y + dy) < (unsigned)H) ? dy * W : 0;
    }

    const float* ap = att + (((size_t)b * 25) << logHW) + remL;
    float a[25];
    #pragma unroll
    for (int t = 0; t < 25; t++){
        const int dy = t / 5 - 2, dx = t % 5 - 2;
        const float mk = (((unsigned)(y + dy) < (unsigned)H) &&
                          ((unsigned)(x + dx) < (unsigned)W)) ? 1.f : 0.f;
        a[t] = ap[(size_t)t << logHW] * mk;
    }

    const int c0 = (blockIdx.y * 4 + wv) * CW;
    const float* fp = frame + (((size_t)b * C + c0) << logHW) + remL;
    float*       op = newf  + (((size_t)b * C + c0) << logHW) + remL;

    for (int ci = 0; ci < CW; ci++){
        float f[5];
        #pragma unroll
        for (int r = 0; r < 5; r++) f[r] = fp[roff[r]];
        float acc = 0.f;
        #pragma unroll
        for (int r = 0; r < 5; r++){
            float v[5];
            v[0] = bperm(adr[0], f[r]);
            v[1] = bperm(adr[1], f[r]);
            v[2] = f[r];
            v[3] = bperm(adr[2], f[r]);
            v[4] = bperm(adr[3], f[r]);
            #pragma unroll
            for (int j = 0; j < 5; j++)
                acc += a[r * 5 + j] * v[j];
        }
        op[0] = acc;
        fp += HW; op += HW;
    }
}

// ============================================================
// gate v2: 3x3, 2 outputs, over concat(key,new). Same row-band
// pattern (3 rows + lane±1 bpermute). Partial z0/z1 LDS-combined,
// atomicAdd into pre-zeroed gz buffer; bias+sigmoid folded into
// prep_gin.
// ============================================================
__global__ __launch_bounds__(256)
void gate_v2(const float* __restrict__ key, const float* __restrict__ newf,
             const float* __restrict__ Wg, float* __restrict__ gz,
             int C, int CW, int H, int W, int logHW, int logW){
    const int tid = threadIdx.x, lane = tid & 63, wv = tid >> 6;
    const int HW = 1 << logHW;
    const int p0 = blockIdx.x * 64;
    const int b  = p0 >> logHW;
    const int remL = (p0 & (HW - 1)) + lane;
    const int y = remL >> logW, x = remL & (W - 1);

    float m[9];
    #pragma unroll
    for (int t = 0; t < 9; t++){
        const int dy = t / 3 - 1, dx = t % 3 - 1;
        m[t] = (((unsigned)(y + dy) < (unsigned)H) &&
                ((unsigned)(x + dx) < (unsigned)W)) ? 1.f : 0.f;
    }
    const int adrL = ((lane - 1) & 63) << 2;
    const int adrR = ((lane + 1) & 63) << 2;

    int roff[3];
    #pragma unroll
    for (int r = 0; r < 3; r++){
        const int dy = r - 1;
        roff[r] = ((unsigned)(y + dy) < (unsigned)H) ? dy * W : 0;
    }

    const int c0 = (blockIdx.y * 4 + wv) * CW;   // u in [0, 2C); chunk never straddles C
    const float* base = (c0 < C)
        ? key  + (((size_t)b * C + c0)       << logHW)
        : newf + (((size_t)b * C + (c0 - C)) << logHW);
    const float* ip = base + remL;

    float z0 = 0.f, z1 = 0.f;
    for (int ci = 0; ci < CW; ci++){
        const int u = c0 + ci;
        const float* w0 = Wg + (size_t)u * 9;
        const float* w1 = Wg + ((size_t)2 * C + u) * 9;
        float f[3];
        #pragma unroll
        for (int r = 0; r < 3; r++) f[r] = ip[roff[r]];
        #pragma unroll
        for (int r = 0; r < 3; r++){
            float v[3];
            v[0] = bperm(adrL, f[r]);
            v[1] = f[r];
            v[2] = bperm(adrR, f[r]);
            #pragma unroll
            for (int j = 0; j < 3; j++){
                const float val = v[j] * m[r * 3 + j];
                z0 += val * w0[r * 3 + j];
                z1 += val * w1[r * 3 + j];
            }
        }
        ip += HW;
    }

    __shared__ float sz[2][4][64];
    sz[0][wv][lane] = z0; sz[1][wv][lane] = z1;
    __syncthreads();
    if (wv < 2){
        const float s = sz[wv][0][lane] + sz[wv][1][lane] +
                        sz[wv][2][lane] + sz[wv][3][lane];
        atomicAdd(gz + ((size_t)b * 2 + wv) * HW + remL, s);
    }
}

// ============================================================
// prep_gin: NCHW fp32 (key,new) * sigmoid(gz+bg) -> NHWC bf16 gin
// ============================================================
__global__ void prep_gin(const float* __restrict__ key, const float* __restrict__ newf,
                         const float* __restrict__ g, const float* __restrict__ bg,
                         unsigned short* __restrict__ gin,
                         int C, int HW){
    __shared__ unsigned short tile[64][65];
    int tid = threadIdx.x;
    int pt0 = blockIdx.x * 64;
    int u0  = blockIdx.y * 64;
    int b   = pt0 / HW;
    int rem0 = pt0 - b * HW;
    const float* gb = g + (size_t)(b * 2) * HW;

    #pragma unroll
    for (int it = 0; it < 16; it++){
        int idx = it * 256 + tid;
        int ur = idx >> 6, pc = idx & 63;
        int u = u0 + ur; int rem = rem0 + pc;
        const float* src; int sel;
        if (u < C){ src = key  + ((size_t)b * C + u) * HW;       sel = 0; }
        else      { src = newf + ((size_t)b * C + (u - C)) * HW; sel = 1; }
        float zz = gb[(size_t)sel * HW + rem] + bg[sel];
        float gv = 1.f / (1.f + expf(-zz));
        float v = src[rem] * gv;
        tile[ur][pc] = f2bf(v);
    }
    __syncthreads();
    unsigned short* go = gin + (size_t)pt0 * (2 * C) + u0;
    #pragma unroll
    for (int it = 0; it < 16; it++){
        int idx = it * 256 + tid;
        int pr = idx >> 6, uc = idx & 63;
        go[(size_t)pr * (2 * C) + uc] = tile[uc][pr];
    }
}

// ============================================================
// prep_w: W[co][ci][t] fp32 -> Wt[co][t*Cin+ci] bf16
// ============================================================
__global__ void prep_w(const float* __restrict__ W, unsigned short* __restrict__ Wt,
                       int Cin){
    int ci = blockIdx.y * 256 + threadIdx.x;
    int bx = blockIdx.x;
    int co = bx / 9, t = bx - co * 9;
    Wt[(size_t)bx * Cin + ci] = f2bf(W[((size_t)co * Cin + ci) * 9 + t]);
}

// ============================================================
// conv_mfma v4b (unchanged from round 3 — verified): deep software
// pipeline, 5 LDS buffers, counted vmcnt, setprio around MFMA.
// ============================================================
template<int BN, int EPI>
__global__ __launch_bounds__(256, 2)
void conv_mfma(const unsigned short* __restrict__ gin,
               const unsigned short* __restrict__ Wt,
               const float* __restrict__ bias,
               unsigned short* __restrict__ obf, int ostride,
               float* __restrict__ of32,
               const void* __restrict__ zp,
               int Cin, int Cout, int H, int W, int logHW, int logW)
{
    constexpr int BM = 64;
    constexpr int BNh = BN / 2;
    constexpr int NJ = BN / 32;
    constexpr int NBUF = 5;
    __shared__ __align__(16) unsigned short sA[NBUF][BM * 32];
    __shared__ __align__(16) unsigned short sB[NBUF][BN * 32];

    const int tid = threadIdx.x;
    const int lane = tid & 63;
    const int wv = tid >> 6;
    const int wm = wv >> 1, wn = wv & 1;
    const int ln = lane & 15, q = lane >> 4;

    const int p0 = blockIdx.x * BM;
    const int b  = p0 >> logHW;
    const int rem0 = p0 - (b << logHW);

    const int rowA0 = tid >> 2;
    const int gc8 = ((tid & 3) ^ ((tid >> 3) & 3)) * 8;    // element offset
    const int remA0 = rem0 + rowA0;
    const int yA0 = remA0 >> logW, xA0 = remA0 & (W - 1);
    const size_t pbase = ((size_t)b << logHW);

    const int nt0 = blockIdx.y * BN;
    const size_t Ktot = (size_t)9 * Cin;
    const unsigned short* wB0 = Wt + (size_t)(nt0 + rowA0) * Ktot + gc8;

    f4v acc[2][NJ];
    #pragma unroll
    for (int i = 0; i < 2; i++)
        #pragma unroll
        for (int j = 0; j < NJ; j++){ f4v z = {0.f, 0.f, 0.f, 0.f}; acc[i][j] = z; }

    const int cblocks = Cin >> 5;
    const int total = 9 * cblocks;

    int sbuf = 0;
    int scb = 0;
    int st  = 0;
    bool sv = (yA0 > 0) && (xA0 > 0);
    const unsigned short* sa  = gin + (pbase + remA0 + (-W - 1)) * Cin + gc8;
    const unsigned short* swb = wB0;

    auto do_stage = [&](){
        gl_lds16(sv ? (const void*)(sa + scb * 32) : zp, (char*)sA[sbuf] + wv * 1024);
        char* dB = (char*)sB[sbuf];
        gl_lds16((const void*)swb, dB + wv * 1024);
        if constexpr (BN == 128)
            gl_lds16((const void*)(swb + (size_t)64 * Ktot), dB + 4096 + wv * 1024);
        swb += 32;
        sbuf = (sbuf == NBUF - 1) ? 0 : sbuf + 1;
        if (++scb == cblocks){
            scb = 0; ++st;
            const int dy = st / 3 - 1, dx = st - (st / 3) * 3 - 1;
            sv = ((unsigned)(yA0 + dy) < (unsigned)H) && ((unsigned)(xA0 + dx) < (unsigned)W);
            sa = gin + (pbase + remA0 + dy * W + dx) * Cin + gc8;
        }
    };

    do_stage(); do_stage(); do_stage();

    const int rchunk = (q ^ ((ln >> 1) & 3)) * 8;
    int cbuf = 0;
    for (int kb = 0; kb < total; kb++){
        if (kb + 2 < total){
            if constexpr (BN == 128) asm volatile("s_waitcnt vmcnt(6)" ::: "memory");
            else                     asm volatile("s_waitcnt vmcnt(4)" ::: "memory");
        } else if (kb + 1 < total){
            if constexpr (BN == 128) asm volatile("s_waitcnt vmcnt(3)" ::: "memory");
            else                     asm volatile("s_waitcnt vmcnt(2)" ::: "memory");
        } else {
            asm volatile("s_waitcnt vmcnt(0)" ::: "memory");
        }
        __builtin_amdgcn_sched_barrier(0);
        __builtin_amdgcn_s_barrier();
        __builtin_amdgcn_sched_barrier(0);
        if (kb + 3 < total) do_stage();

        const unsigned short* A = sA[cbuf];
        const unsigned short* B = sB[cbuf];
        cbuf = (cbuf == NBUF - 1) ? 0 : cbuf + 1;

        s8v af[2];
        #pragma unroll
        for (int i = 0; i < 2; i++)
            af[i] = *(const s8v*)(A + (wm * 32 + i * 16 + ln) * 32 + rchunk);
        __builtin_amdgcn_s_setprio(1);
        #pragma unroll
        for (int j = 0; j < NJ; j++){
            s8v bfr = *(const s8v*)(B + (wn * BNh + j * 16 + ln) * 32 + rchunk);
            #pragma unroll
            for (int i = 0; i < 2; i++)
                acc[i][j] = mfma16(af[i], bfr, acc[i][j]);
        }
        __builtin_amdgcn_s_setprio(0);
    }

    #pragma unroll
    for (int i = 0; i < 2; i++){
        const int m0 = wm * 32 + i * 16 + q * 4;
        const int p = p0 + m0;
        #pragma unroll
        for (int j = 0; j < NJ; j++){
            const int n = nt0 + wn * BNh + j * 16 + ln;
            const float bv = bias[n];
            if (EPI == 0){
                #pragma unroll
                for (int r = 0; r < 4; r++){
                    float v = fmaxf(acc[i][j][r] + bv, 0.f);
                    obf[(size_t)(p + r) * ostride + n] = f2bf(v);
                }
            } else {
                f4v o;
                #pragma unroll
                for (int r = 0; r < 4; r++) o[r] = fmaxf(acc[i][j][r] + bv, 0.f);
                const int rem = rem0 + m0;
                *(f4v*)(of32 + (((size_t)b * Cout + n) << logHW) + rem) = o;
            }
        }
    }
}

// ============================================================
extern "C" void kernel_launch(void* const* d_in, const int* in_sizes, int n_in,
                              void* d_out, int out_size, void* d_ws, size_t ws_size,
                              hipStream_t stream){
    (void)in_sizes; (void)n_in; (void)out_size; (void)ws_size;

    const float* X[4][2];
    for (int s = 0; s < 4; s++)
        for (int l = 0; l < 2; l++)
            X[s][l] = (const float*)d_in[s * 2 + l];
    const float* Wg[2] = { (const float*)d_in[8],  (const float*)d_in[14] };
    const float* bg[2] = { (const float*)d_in[9],  (const float*)d_in[15] };
    const float* Wd[2] = { (const float*)d_in[10], (const float*)d_in[16] };
    const float* bd[2] = { (const float*)d_in[11], (const float*)d_in[17] };
    const float* Wc[2] = { (const float*)d_in[12], (const float*)d_in[18] };
    const float* bc[2] = { (const float*)d_in[13], (const float*)d_in[19] };
    float* out = (float*)d_out;

    char* ws = (char*)d_ws;
    unsigned* gmax = (unsigned*)ws;
    const void* zp = (const void*)(ws + 1024);
    float* corrbuf = (float*)(ws + 4096);
    float* newbuf  = (float*)(ws + 4096 + 1638400);
    unsigned short* wtbuf = (unsigned short*)newbuf;   // alias, disjoint lifetime
    float* gbuf    = (float*)(ws + 4096 + 1638400 + 16777216);
    unsigned short* ginbuf = (unsigned short*)(ws + 4096 + 1638400 + 16777216 + 131072);
    unsigned short* totbuf = (unsigned short*)(ws + 4096 + 1638400 + 16777216 + 131072 + 16777216);

    hipMemsetAsync(ws, 0, 4096, stream);

    const int Cs[2] = {256, 512};
    const int Hs[2] = {64, 32};
    const int logWs[2] = {6, 5};
    const int logHWs[2] = {12, 10};
    const size_t outOff[2] = {0, (size_t)4 * 256 * 4096};

    for (int l = 0; l < 2; l++){
        const int C = Cs[l], H = Hs[l], W = Hs[l], HW = H * W;
        const int logW = logWs[l], logHW = logHWs[l];
        const float* key = X[3][l];
        const int pblk = 4 * HW / 256;
        const int Mt = 4 * HW / 64;            // BM=64 tiles

        const int gx  = 4 * HW / 64;           // row-band tiles: {256, 64}
        const int S   = (l == 0) ? 2 : 8;      // c-split across grid.y -> 512 blocks
        const int CWc = C / (4 * S);           // channels per wave (corr/warp)
        const int CWg = (2 * C) / (4 * S);     // channels per wave (gate)

        for (int s = 0; s < 3; s++){
            const float* fr = X[s][l];
            unsigned* slot = gmax + (l * 3 + s);
            hipMemsetAsync(corrbuf, 0, (size_t)4 * 25 * HW * 4, stream);
            hipMemsetAsync(gbuf,    0, (size_t)4 * 2 * HW * 4, stream);
            corr_v2<<<dim3(gx, S), 256, 0, stream>>>(
                key, fr, corrbuf, C, CWc, H, W, logHW, logW);
            max_kernel<<<25 * 4 * HW / 256, 256, 0, stream>>>(corrbuf, slot);
            att_kernel<<<pblk, 256, 0, stream>>>(corrbuf, slot, logHW);
            warp_v2<<<dim3(gx, S), 256, 0, stream>>>(
                fr, corrbuf, newbuf, C, CWc, H, W, logHW, logW);
            gate_v2<<<dim3(gx, S), 256, 0, stream>>>(
                key, newbuf, Wg[l] + (size_t)s * 2 * (2 * C) * 9,
                gbuf, C, CWg, H, W, logHW, logW);
            prep_gin<<<dim3(4 * HW / 64, 2 * C / 64), 256, 0, stream>>>(
                key, newbuf, gbuf, bg[l] + (size_t)s * 2, ginbuf, C, HW);
            prep_w<<<dim3(C * 9, 2 * C / 256), 256, 0, stream>>>(
                Wd[l] + (size_t)s * C * 2 * C * 9, wtbuf, 2 * C);
            if (l == 0)
                conv_mfma<128, 0><<<dim3(Mt, C / 128), 256, 0, stream>>>(
                    ginbuf, wtbuf, bd[l] + s * C, totbuf + s * C, 3 * C,
                    nullptr, zp, 2 * C, C, H, W, logHW, logW);
            else
                conv_mfma<64, 0><<<dim3(Mt, C / 64), 256, 0, stream>>>(
                    ginbuf, wtbuf, bd[l] + s * C, totbuf + s * C, 3 * C,
                    nullptr, zp, 2 * C, C, H, W, logHW, logW);
        }
        prep_w<<<dim3(C * 9, 3 * C / 256), 256, 0, stream>>>(Wc[l], wtbuf, 3 * C);
        if (l == 0)
            conv_mfma<128, 1><<<dim3(Mt, 2), 256, 0, stream>>>(
                totbuf, wtbuf, bc[l], nullptr, 0,
                out + outOff[l], zp, 3 * C, C, H, W, logHW, logW);
        else
            conv_mfma<64, 1><<<dim3(Mt, 8), 256, 0, stream>>>(
                totbuf, wtbuf, bc[l], nullptr, 0,
                out + outOff[l], zp, 3 * C, C, H, W, logHW, logW);
    }
}

// Round 6
// 1929.366 us; speedup vs baseline: 1.4609x; 1.0925x over previous
//
#include <hip/hip_runtime.h>
#include <hip/hip_bf16.h>
#include <math.h>

#define PAD 2

typedef __attribute__((ext_vector_type(8))) short s8v;    // 8 bf16 = 4 VGPRs
typedef __attribute__((ext_vector_type(4))) float f4v;    // 4 fp32 acc

__device__ __forceinline__ f4v mfma16(s8v a, s8v b, f4v c){
    return __builtin_amdgcn_mfma_f32_16x16x32_bf16(a, b, c, 0, 0, 0);
}

__device__ __forceinline__ unsigned short f2bf(float f){
    unsigned u = __float_as_uint(f);
    unsigned r = u + 0x7FFFu + ((u >> 16) & 1u);
    return (unsigned short)(r >> 16);
}

// ---- ordered-uint encoding for float atomicMax ----
__device__ __forceinline__ unsigned f2o(float f){
    unsigned b = __float_as_uint(f);
    return (b & 0x80000000u) ? ~b : (b | 0x80000000u);
}
__device__ __forceinline__ float o2f(unsigned u){
    return __uint_as_float((u & 0x80000000u) ? (u & 0x7fffffffu) : ~u);
}

__device__ __forceinline__ float bperm(int adr, float v){
    return __uint_as_float((unsigned)__builtin_amdgcn_ds_bpermute(adr, (int)__float_as_uint(v)));
}

// ============================================================
// corr v2 (verified r5): wave = 64-px row-band; tap shifts via
// ds_bpermute; c-split LDS-combined + atomicAdd.
// ============================================================
__global__ __launch_bounds__(256)
void corr_v2(const float* __restrict__ key, const float* __restrict__ frame,
             float* __restrict__ corr,
             int C, int CW, int H, int W, int logHW, int logW){
    const int tid = threadIdx.x, lane = tid & 63, wv = tid >> 6;
    const int HW = 1 << logHW;
    const int p0 = blockIdx.x * 64;
    const int b  = p0 >> logHW;
    const int remL = (p0 & (HW - 1)) + lane;
    const int y = remL >> logW, x = remL & (W - 1);

    float m[25];
    #pragma unroll
    for (int t = 0; t < 25; t++){
        const int dy = t / 5 - 2, dx = t % 5 - 2;
        m[t] = (((unsigned)(y + dy) < (unsigned)H) &&
                ((unsigned)(x + dx) < (unsigned)W)) ? 1.f : 0.f;
    }
    int adr[4];
    const int dxs[4] = {-2, -1, 1, 2};
    #pragma unroll
    for (int i = 0; i < 4; i++) adr[i] = ((lane + dxs[i]) & 63) << 2;

    int roff[5];
    #pragma unroll
    for (int r = 0; r < 5; r++){
        const int dy = r - 2;
        roff[r] = ((unsigned)(y + dy) < (unsigned)H) ? dy * W : 0;
    }

    const int c0 = (blockIdx.y * 4 + wv) * CW;
    const float* kp = key   + (((size_t)b * C + c0) << logHW) + remL;
    const float* fp = frame + (((size_t)b * C + c0) << logHW) + remL;

    float acc[25];
    #pragma unroll
    for (int t = 0; t < 25; t++) acc[t] = 0.f;

    for (int ci = 0; ci < CW; ci++){
        const float k = kp[0];
        float f[5];
        #pragma unroll
        for (int r = 0; r < 5; r++) f[r] = fp[roff[r]];
        #pragma unroll
        for (int r = 0; r < 5; r++){
            float v[5];
            v[0] = bperm(adr[0], f[r]);
            v[1] = bperm(adr[1], f[r]);
            v[2] = f[r];
            v[3] = bperm(adr[2], f[r]);
            v[4] = bperm(adr[3], f[r]);
            #pragma unroll
            for (int j = 0; j < 5; j++)
                acc[r * 5 + j] += k * (v[j] * m[r * 5 + j]);
        }
        kp += HW; fp += HW;
    }

    __shared__ float sacc[4][25][64];
    #pragma unroll
    for (int t = 0; t < 25; t++) sacc[wv][t][lane] = acc[t];
    __syncthreads();
    #pragma unroll
    for (int tg = 0; tg < 7; tg++){
        const int t = wv + tg * 4;
        if (t < 25){
            const float s = sacc[0][t][lane] + sacc[1][t][lane] +
                            sacc[2][t][lane] + sacc[3][t][lane];
            atomicAdd(corr + (((size_t)b * 25 + t) << logHW) + remL, s);
        }
    }
}

// ============================================================
// global max over the summed corr buffer (runs after corr_v2).
// ============================================================
__global__ void max_kernel(const float* __restrict__ corr, unsigned* __restrict__ gmax){
    float v = corr[(size_t)blockIdx.x * 256 + threadIdx.x];
    #pragma unroll
    for (int o = 32; o > 0; o >>= 1) v = fmaxf(v, __shfl_down(v, o));
    if ((threadIdx.x & 63) == 0) atomicMax(gmax, f2o(v));
}

// ============================================================
// att: softmax over the 25 offsets, in-place on corr buffer.
// ============================================================
__global__ void att_kernel(float* __restrict__ corr, const unsigned* __restrict__ gmax,
                           int logHW){
    const int p = blockIdx.x * 256 + threadIdx.x;
    const int b = p >> logHW;
    const int rem = p & ((1 << logHW) - 1);
    float* cp = corr + (((size_t)b * 25) << logHW) + rem;
    const float scale = 20.f / o2f(*gmax);

    float z[25]; float m = -INFINITY;
    #pragma unroll
    for (int k = 0; k < 25; k++){
        z[k] = cp[k << logHW] * scale;
        m = fmaxf(m, z[k]);
    }
    float s = 0.f;
    #pragma unroll
    for (int k = 0; k < 25; k++){ z[k] = expf(z[k] - m); s += z[k]; }
    const float inv = 1.f / s;
    #pragma unroll
    for (int k = 0; k < 25; k++) cp[k << logHW] = z[k] * inv;
}

// ============================================================
// warp v2 (verified r5)
// ============================================================
__global__ __launch_bounds__(256)
void warp_v2(const float* __restrict__ frame, const float* __restrict__ att,
             float* __restrict__ newf,
             int C, int CW, int H, int W, int logHW, int logW){
    const int tid = threadIdx.x, lane = tid & 63, wv = tid >> 6;
    const int HW = 1 << logHW;
    const int p0 = blockIdx.x * 64;
    const int b  = p0 >> logHW;
    const int remL = (p0 & (HW - 1)) + lane;
    const int y = remL >> logW, x = remL & (W - 1);

    int adr[4];
    const int dxs[4] = {-2, -1, 1, 2};
    #pragma unroll
    for (int i = 0; i < 4; i++) adr[i] = ((lane + dxs[i]) & 63) << 2;

    int roff[5];
    #pragma unroll
    for (int r = 0; r < 5; r++){
        const int dy = r - 2;
        roff[r] = ((unsigned)(y + dy) < (unsigned)H) ? dy * W : 0;
    }

    const float* ap = att + (((size_t)b * 25) << logHW) + remL;
    float a[25];
    #pragma unroll
    for (int t = 0; t < 25; t++){
        const int dy = t / 5 - 2, dx = t % 5 - 2;
        const float mk = (((unsigned)(y + dy) < (unsigned)H) &&
                          ((unsigned)(x + dx) < (unsigned)W)) ? 1.f : 0.f;
        a[t] = ap[(size_t)t << logHW] * mk;
    }

    const int c0 = (blockIdx.y * 4 + wv) * CW;
    const float* fp = frame + (((size_t)b * C + c0) << logHW) + remL;
    float*       op = newf  + (((size_t)b * C + c0) << logHW) + remL;

    for (int ci = 0; ci < CW; ci++){
        float f[5];
        #pragma unroll
        for (int r = 0; r < 5; r++) f[r] = fp[roff[r]];
        float acc = 0.f;
        #pragma unroll
        for (int r = 0; r < 5; r++){
            float v[5];
            v[0] = bperm(adr[0], f[r]);
            v[1] = bperm(adr[1], f[r]);
            v[2] = f[r];
            v[3] = bperm(adr[2], f[r]);
            v[4] = bperm(adr[3], f[r]);
            #pragma unroll
            for (int j = 0; j < 5; j++)
                acc += a[r * 5 + j] * v[j];
        }
        op[0] = acc;
        fp += HW; op += HW;
    }
}

// ============================================================
// gate v2 (verified r5)
// ============================================================
__global__ __launch_bounds__(256)
void gate_v2(const float* __restrict__ key, const float* __restrict__ newf,
             const float* __restrict__ Wg, float* __restrict__ gz,
             int C, int CW, int H, int W, int logHW, int logW){
    const int tid = threadIdx.x, lane = tid & 63, wv = tid >> 6;
    const int HW = 1 << logHW;
    const int p0 = blockIdx.x * 64;
    const int b  = p0 >> logHW;
    const int remL = (p0 & (HW - 1)) + lane;
    const int y = remL >> logW, x = remL & (W - 1);

    float m[9];
    #pragma unroll
    for (int t = 0; t < 9; t++){
        const int dy = t / 3 - 1, dx = t % 3 - 1;
        m[t] = (((unsigned)(y + dy) < (unsigned)H) &&
                ((unsigned)(x + dx) < (unsigned)W)) ? 1.f : 0.f;
    }
    const int adrL = ((lane - 1) & 63) << 2;
    const int adrR = ((lane + 1) & 63) << 2;

    int roff[3];
    #pragma unroll
    for (int r = 0; r < 3; r++){
        const int dy = r - 1;
        roff[r] = ((unsigned)(y + dy) < (unsigned)H) ? dy * W : 0;
    }

    const int c0 = (blockIdx.y * 4 + wv) * CW;   // u in [0, 2C); chunk never straddles C
    const float* base = (c0 < C)
        ? key  + (((size_t)b * C + c0)       << logHW)
        : newf + (((size_t)b * C + (c0 - C)) << logHW);
    const float* ip = base + remL;

    float z0 = 0.f, z1 = 0.f;
    for (int ci = 0; ci < CW; ci++){
        const int u = c0 + ci;
        const float* w0 = Wg + (size_t)u * 9;
        const float* w1 = Wg + ((size_t)2 * C + u) * 9;
        float f[3];
        #pragma unroll
        for (int r = 0; r < 3; r++) f[r] = ip[roff[r]];
        #pragma unroll
        for (int r = 0; r < 3; r++){
            float v[3];
            v[0] = bperm(adrL, f[r]);
            v[1] = f[r];
            v[2] = bperm(adrR, f[r]);
            #pragma unroll
            for (int j = 0; j < 3; j++){
                const float val = v[j] * m[r * 3 + j];
                z0 += val * w0[r * 3 + j];
                z1 += val * w1[r * 3 + j];
            }
        }
        ip += HW;
    }

    __shared__ float sz[2][4][64];
    sz[0][wv][lane] = z0; sz[1][wv][lane] = z1;
    __syncthreads();
    if (wv < 2){
        const float s = sz[wv][0][lane] + sz[wv][1][lane] +
                        sz[wv][2][lane] + sz[wv][3][lane];
        atomicAdd(gz + ((size_t)b * 2 + wv) * HW + remL, s);
    }
}

// ============================================================
// prep_gin: NCHW fp32 (key,new) * sigmoid(gz+bg) -> NHWC bf16 gin
// ============================================================
__global__ void prep_gin(const float* __restrict__ key, const float* __restrict__ newf,
                         const float* __restrict__ g, const float* __restrict__ bg,
                         unsigned short* __restrict__ gin,
                         int C, int HW){
    __shared__ unsigned short tile[64][65];
    int tid = threadIdx.x;
    int pt0 = blockIdx.x * 64;
    int u0  = blockIdx.y * 64;
    int b   = pt0 / HW;
    int rem0 = pt0 - b * HW;
    const float* gb = g + (size_t)(b * 2) * HW;

    #pragma unroll
    for (int it = 0; it < 16; it++){
        int idx = it * 256 + tid;
        int ur = idx >> 6, pc = idx & 63;
        int u = u0 + ur; int rem = rem0 + pc;
        const float* src; int sel;
        if (u < C){ src = key  + ((size_t)b * C + u) * HW;       sel = 0; }
        else      { src = newf + ((size_t)b * C + (u - C)) * HW; sel = 1; }
        float zz = gb[(size_t)sel * HW + rem] + bg[sel];
        float gv = 1.f / (1.f + expf(-zz));
        float v = src[rem] * gv;
        tile[ur][pc] = f2bf(v);
    }
    __syncthreads();
    unsigned short* go = gin + (size_t)pt0 * (2 * C) + u0;
    #pragma unroll
    for (int it = 0; it < 16; it++){
        int idx = it * 256 + tid;
        int pr = idx >> 6, uc = idx & 63;
        go[(size_t)pr * (2 * C) + uc] = tile[uc][pr];
    }
}

// ============================================================
// prep_w: W[co][ci][t] fp32 -> Wt[co][t*Cin+ci] bf16
// ============================================================
__global__ void prep_w(const float* __restrict__ W, unsigned short* __restrict__ Wt,
                       int Cin){
    int ci = blockIdx.y * 256 + threadIdx.x;
    int bx = blockIdx.x;
    int co = bx / 9, t = bx - co * 9;
    Wt[(size_t)bx * Cin + ci] = f2bf(W[((size_t)co * Cin + ci) * 9 + t]);
}

// ============================================================
// conv_mfma v5: REGISTER-STAGED pipeline (T14). v3/v4b were both
// ~183us (MfmaUtil 12.6%) regardless of sync depth -> the limiter
// is the global_load_lds DMA path (~5 instr in flight/CU). Switch
// to global_load_dwordx4 -> VGPR -> ds_write_b128: deep MSHR
// concurrency on the normal load-return path. 2 LDS buffers; loads
// issued 2 iterations ahead via named reg sets R0/R1 (rule #20:
// static indexing, manual x2 unroll); counted vmcnt; lgkmcnt(0)+
// s_barrier per step; setprio around MFMA.
// ============================================================
template<int BN, int EPI>
__global__ __launch_bounds__(256, 2)
void conv_mfma(const unsigned short* __restrict__ gin,
               const unsigned short* __restrict__ Wt,
               const float* __restrict__ bias,
               unsigned short* __restrict__ obf, int ostride,
               float* __restrict__ of32,
               const void* __restrict__ zp,
               int Cin, int Cout, int H, int W, int logHW, int logW)
{
    constexpr int BM = 64;
    constexpr int BNh = BN / 2;
    constexpr int NJ = BN / 32;
    __shared__ __align__(16) unsigned short sA[2][BM * 32];
    __shared__ __align__(16) unsigned short sB[2][BN * 32];

    const int tid = threadIdx.x;
    const int lane = tid & 63;
    const int wv = tid >> 6;
    const int wm = wv >> 1, wn = wv & 1;
    const int ln = lane & 15, q = lane >> 4;

    const int p0 = blockIdx.x * BM;
    const int b  = p0 >> logHW;
    const int rem0 = p0 - (b << logHW);

    // staging: row = tid>>2 (0..63); swizzled global chunk
    const int rowA0 = tid >> 2;
    const int gc8 = ((tid & 3) ^ ((tid >> 3) & 3)) * 8;    // element offset
    const int remA0 = rem0 + rowA0;
    const int yA0 = remA0 >> logW, xA0 = remA0 & (W - 1);
    const size_t pbase = ((size_t)b << logHW);

    const int nt0 = blockIdx.y * BN;
    const size_t Ktot = (size_t)9 * Cin;
    const unsigned short* wB0 = Wt + (size_t)(nt0 + rowA0) * Ktot + gc8;

    f4v acc[2][NJ];
    #pragma unroll
    for (int i = 0; i < 2; i++)
        #pragma unroll
        for (int j = 0; j < NJ; j++){ f4v z = {0.f, 0.f, 0.f, 0.f}; acc[i][j] = z; }

    const int cblocks = Cin >> 5;
    const int total = 9 * cblocks;   // always even (144/216/288/432)

    // staging-cursor state (for the NEXT K-block to issue)
    int scb = 0;                                   // k-chunk within tap
    int st  = 0;                                   // tap index
    bool sv = (yA0 > 0) && (xA0 > 0);              // tap 0: dy=-1,dx=-1
    const unsigned short* sa  = gin + (pbase + remA0 + (-W - 1)) * Cin + gc8;
    const unsigned short* swb = wB0;               // +32 per issued K-block

    struct Regs { f4v a, b0, b1; };
    Regs R0, R1;

    auto issue = [&](Regs& r){
        r.a  = *(const f4v*)(sv ? (const void*)(sa + scb * 32) : zp);
        r.b0 = *(const f4v*)swb;
        if constexpr (BN == 128) r.b1 = *(const f4v*)(swb + (size_t)64 * Ktot);
        swb += 32;
        if (++scb == cblocks){
            scb = 0; ++st;
            const int dy = st / 3 - 1, dx = st - (st / 3) * 3 - 1;
            sv = ((unsigned)(yA0 + dy) < (unsigned)H) && ((unsigned)(xA0 + dx) < (unsigned)W);
            sa = gin + (pbase + remA0 + dy * W + dx) * Cin + gc8;
        }
    };
    auto commit = [&](const Regs& r, int bsel){
        *(f4v*)((char*)sA[bsel] + (size_t)tid * 16) = r.a;
        char* dB = (char*)sB[bsel];
        *(f4v*)(dB + (size_t)tid * 16) = r.b0;
        if constexpr (BN == 128) *(f4v*)(dB + 4096 + (size_t)tid * 16) = r.b1;
    };

    const int rchunk = (q ^ ((ln >> 1) & 3)) * 8;   // swizzled read offset
    auto compute = [&](int bsel){
        const unsigned short* A = sA[bsel];
        const unsigned short* B = sB[bsel];
        s8v af[2];
        #pragma unroll
        for (int i = 0; i < 2; i++)
            af[i] = *(const s8v*)(A + (wm * 32 + i * 16 + ln) * 32 + rchunk);
        __builtin_amdgcn_s_setprio(1);
        #pragma unroll
        for (int j = 0; j < NJ; j++){
            s8v bfr = *(const s8v*)(B + (wn * BNh + j * 16 + ln) * 32 + rchunk);
            #pragma unroll
            for (int i = 0; i < 2; i++)
                acc[i][j] = mfma16(af[i], bfr, acc[i][j]);
        }
        __builtin_amdgcn_s_setprio(0);
    };

    // vmcnt literal = loads-per-issue (BN==128 -> 3, else 2)
    #define WAIT_CUR()  do{ if constexpr (BN == 128) asm volatile("s_waitcnt vmcnt(3)" ::: "memory"); \
                            else                     asm volatile("s_waitcnt vmcnt(2)" ::: "memory"); }while(0)
    #define WAIT_ALL()  asm volatile("s_waitcnt vmcnt(0)" ::: "memory")

    issue(R0); issue(R1);                // K-blocks 0 and 1 in flight

    for (int kb = 0; kb < total; kb += 2){
        // ---- even sub-step: data in R0, buffer kb&1 == 0 ----
        if (kb + 1 < total) WAIT_CUR(); else WAIT_ALL();
        __builtin_amdgcn_sched_barrier(0);
        commit(R0, 0);
        if (kb + 2 < total) issue(R0);   // K-block kb+2
        asm volatile("s_waitcnt lgkmcnt(0)" ::: "memory");
        __builtin_amdgcn_sched_barrier(0);
        __builtin_amdgcn_s_barrier();
        compute(0);

        // ---- odd sub-step: data in R1, buffer 1 ----
        const int kb1 = kb + 1;
        if (kb1 + 1 < total) WAIT_CUR(); else WAIT_ALL();
        __builtin_amdgcn_sched_barrier(0);
        commit(R1, 1);
        if (kb1 + 2 < total) issue(R1);  // K-block kb+3
        asm volatile("s_waitcnt lgkmcnt(0)" ::: "memory");
        __builtin_amdgcn_sched_barrier(0);
        __builtin_amdgcn_s_barrier();
        compute(1);
    }
    #undef WAIT_CUR
    #undef WAIT_ALL

    // epilogue: D rows m = q*4+r (pixels), cols n = ln (cout)
    #pragma unroll
    for (int i = 0; i < 2; i++){
        const int m0 = wm * 32 + i * 16 + q * 4;
        const int p = p0 + m0;
        #pragma unroll
        for (int j = 0; j < NJ; j++){
            const int n = nt0 + wn * BNh + j * 16 + ln;
            const float bv = bias[n];
            if (EPI == 0){
                #pragma unroll
                for (int r = 0; r < 4; r++){
                    float v = fmaxf(acc[i][j][r] + bv, 0.f);
                    obf[(size_t)(p + r) * ostride + n] = f2bf(v);
                }
            } else {
                f4v o;
                #pragma unroll
                for (int r = 0; r < 4; r++) o[r] = fmaxf(acc[i][j][r] + bv, 0.f);
                const int rem = rem0 + m0;
                *(f4v*)(of32 + (((size_t)b * Cout + n) << logHW) + rem) = o;
            }
        }
    }
}

// ============================================================
extern "C" void kernel_launch(void* const* d_in, const int* in_sizes, int n_in,
                              void* d_out, int out_size, void* d_ws, size_t ws_size,
                              hipStream_t stream){
    (void)in_sizes; (void)n_in; (void)out_size; (void)ws_size;

    const float* X[4][2];
    for (int s = 0; s < 4; s++)
        for (int l = 0; l < 2; l++)
            X[s][l] = (const float*)d_in[s * 2 + l];
    const float* Wg[2] = { (const float*)d_in[8],  (const float*)d_in[14] };
    const float* bg[2] = { (const float*)d_in[9],  (const float*)d_in[15] };
    const float* Wd[2] = { (const float*)d_in[10], (const float*)d_in[16] };
    const float* bd[2] = { (const float*)d_in[11], (const float*)d_in[17] };
    const float* Wc[2] = { (const float*)d_in[12], (const float*)d_in[18] };
    const float* bc[2] = { (const float*)d_in[13], (const float*)d_in[19] };
    float* out = (float*)d_out;

    char* ws = (char*)d_ws;
    unsigned* gmax = (unsigned*)ws;
    const void* zp = (const void*)(ws + 1024);
    float* corrbuf = (float*)(ws + 4096);
    float* newbuf  = (float*)(ws + 4096 + 1638400);
    unsigned short* wtbuf = (unsigned short*)newbuf;   // alias, disjoint lifetime
    float* gbuf    = (float*)(ws + 4096 + 1638400 + 16777216);
    unsigned short* ginbuf = (unsigned short*)(ws + 4096 + 1638400 + 16777216 + 131072);
    unsigned short* totbuf = (unsigned short*)(ws + 4096 + 1638400 + 16777216 + 131072 + 16777216);

    hipMemsetAsync(ws, 0, 4096, stream);

    const int Cs[2] = {256, 512};
    const int Hs[2] = {64, 32};
    const int logWs[2] = {6, 5};
    const int logHWs[2] = {12, 10};
    const size_t outOff[2] = {0, (size_t)4 * 256 * 4096};

    for (int l = 0; l < 2; l++){
        const int C = Cs[l], H = Hs[l], W = Hs[l], HW = H * W;
        const int logW = logWs[l], logHW = logHWs[l];
        const float* key = X[3][l];
        const int pblk = 4 * HW / 256;
        const int Mt = 4 * HW / 64;            // BM=64 tiles

        const int gx  = 4 * HW / 64;           // row-band tiles: {256, 64}
        const int S   = (l == 0) ? 2 : 8;      // c-split across grid.y -> 512 blocks
        const int CWc = C / (4 * S);           // channels per wave (corr/warp)
        const int CWg = (2 * C) / (4 * S);     // channels per wave (gate)

        for (int s = 0; s < 3; s++){
            const float* fr = X[s][l];
            unsigned* slot = gmax + (l * 3 + s);
            hipMemsetAsync(corrbuf, 0, (size_t)4 * 25 * HW * 4, stream);
            hipMemsetAsync(gbuf,    0, (size_t)4 * 2 * HW * 4, stream);
            corr_v2<<<dim3(gx, S), 256, 0, stream>>>(
                key, fr, corrbuf, C, CWc, H, W, logHW, logW);
            max_kernel<<<25 * 4 * HW / 256, 256, 0, stream>>>(corrbuf, slot);
            att_kernel<<<pblk, 256, 0, stream>>>(corrbuf, slot, logHW);
            warp_v2<<<dim3(gx, S), 256, 0, stream>>>(
                fr, corrbuf, newbuf, C, CWc, H, W, logHW, logW);
            gate_v2<<<dim3(gx, S), 256, 0, stream>>>(
                key, newbuf, Wg[l] + (size_t)s * 2 * (2 * C) * 9,
                gbuf, C, CWg, H, W, logHW, logW);
            prep_gin<<<dim3(4 * HW / 64, 2 * C / 64), 256, 0, stream>>>(
                key, newbuf, gbuf, bg[l] + (size_t)s * 2, ginbuf, C, HW);
            prep_w<<<dim3(C * 9, 2 * C / 256), 256, 0, stream>>>(
                Wd[l] + (size_t)s * C * 2 * C * 9, wtbuf, 2 * C);
            if (l == 0)
                conv_mfma<128, 0><<<dim3(Mt, C / 128), 256, 0, stream>>>(
                    ginbuf, wtbuf, bd[l] + s * C, totbuf + s * C, 3 * C,
                    nullptr, zp, 2 * C, C, H, W, logHW, logW);
            else
                conv_mfma<64, 0><<<dim3(Mt, C / 64), 256, 0, stream>>>(
                    ginbuf, wtbuf, bd[l] + s * C, totbuf + s * C, 3 * C,
                    nullptr, zp, 2 * C, C, H, W, logHW, logW);
        }
        prep_w<<<dim3(C * 9, 3 * C / 256), 256, 0, stream>>>(Wc[l], wtbuf, 3 * C);
        if (l == 0)
            conv_mfma<128, 1><<<dim3(Mt, 2), 256, 0, stream>>>(
                totbuf, wtbuf, bc[l], nullptr, 0,
                out + outOff[l], zp, 3 * C, C, H, W, logHW, logW);
        else
            conv_mfma<64, 1><<<dim3(Mt, 8), 256, 0, stream>>>(
                totbuf, wtbuf, bc[l], nullptr, 0,
                out + outOff[l], zp, 3 * C, C, H, W, logHW, logW);
    }
}

// Round 7
// 1796.346 us; speedup vs baseline: 1.5691x; 1.0741x over previous
//
#include <hip/hip_runtime.h>
#include <hip/hip_bf16.h>
#include <math.h>

#define PAD 2

typedef __attribute__((ext_vector_type(8))) short s8v;    // 8 bf16 = 4 VGPRs
typedef __attribute__((ext_vector_type(4))) float f4v;    // 4 fp32 acc

__device__ __forceinline__ f4v mfma16(s8v a, s8v b, f4v c){
    return __builtin_amdgcn_mfma_f32_16x16x32_bf16(a, b, c, 0, 0, 0);
}

__device__ __forceinline__ unsigned short f2bf(float f){
    unsigned u = __float_as_uint(f);
    unsigned r = u + 0x7FFFu + ((u >> 16) & 1u);
    return (unsigned short)(r >> 16);
}

// ---- ordered-uint encoding for float atomicMax ----
__device__ __forceinline__ unsigned f2o(float f){
    unsigned b = __float_as_uint(f);
    return (b & 0x80000000u) ? ~b : (b | 0x80000000u);
}
__device__ __forceinline__ float o2f(unsigned u){
    return __uint_as_float((u & 0x80000000u) ? (u & 0x7fffffffu) : ~u);
}

__device__ __forceinline__ float bperm(int adr, float v){
    return __uint_as_float((unsigned)__builtin_amdgcn_ds_bpermute(adr, (int)__float_as_uint(v)));
}

// ============================================================
// corr v2 (verified r5): wave = 64-px row-band; tap shifts via
// ds_bpermute; c-split LDS-combined + atomicAdd.
// ============================================================
__global__ __launch_bounds__(256)
void corr_v2(const float* __restrict__ key, const float* __restrict__ frame,
             float* __restrict__ corr,
             int C, int CW, int H, int W, int logHW, int logW){
    const int tid = threadIdx.x, lane = tid & 63, wv = tid >> 6;
    const int HW = 1 << logHW;
    const int p0 = blockIdx.x * 64;
    const int b  = p0 >> logHW;
    const int remL = (p0 & (HW - 1)) + lane;
    const int y = remL >> logW, x = remL & (W - 1);

    float m[25];
    #pragma unroll
    for (int t = 0; t < 25; t++){
        const int dy = t / 5 - 2, dx = t % 5 - 2;
        m[t] = (((unsigned)(y + dy) < (unsigned)H) &&
                ((unsigned)(x + dx) < (unsigned)W)) ? 1.f : 0.f;
    }
    int adr[4];
    const int dxs[4] = {-2, -1, 1, 2};
    #pragma unroll
    for (int i = 0; i < 4; i++) adr[i] = ((lane + dxs[i]) & 63) << 2;

    int roff[5];
    #pragma unroll
    for (int r = 0; r < 5; r++){
        const int dy = r - 2;
        roff[r] = ((unsigned)(y + dy) < (unsigned)H) ? dy * W : 0;
    }

    const int c0 = (blockIdx.y * 4 + wv) * CW;
    const float* kp = key   + (((size_t)b * C + c0) << logHW) + remL;
    const float* fp = frame + (((size_t)b * C + c0) << logHW) + remL;

    float acc[25];
    #pragma unroll
    for (int t = 0; t < 25; t++) acc[t] = 0.f;

    for (int ci = 0; ci < CW; ci++){
        const float k = kp[0];
        float f[5];
        #pragma unroll
        for (int r = 0; r < 5; r++) f[r] = fp[roff[r]];
        #pragma unroll
        for (int r = 0; r < 5; r++){
            float v[5];
            v[0] = bperm(adr[0], f[r]);
            v[1] = bperm(adr[1], f[r]);
            v[2] = f[r];
            v[3] = bperm(adr[2], f[r]);
            v[4] = bperm(adr[3], f[r]);
            #pragma unroll
            for (int j = 0; j < 5; j++)
                acc[r * 5 + j] += k * (v[j] * m[r * 5 + j]);
        }
        kp += HW; fp += HW;
    }

    __shared__ float sacc[4][25][64];
    #pragma unroll
    for (int t = 0; t < 25; t++) sacc[wv][t][lane] = acc[t];
    __syncthreads();
    #pragma unroll
    for (int tg = 0; tg < 7; tg++){
        const int t = wv + tg * 4;
        if (t < 25){
            const float s = sacc[0][t][lane] + sacc[1][t][lane] +
                            sacc[2][t][lane] + sacc[3][t][lane];
            atomicAdd(corr + (((size_t)b * 25 + t) << logHW) + remL, s);
        }
    }
}

// ============================================================
// global max over the summed corr buffer (runs after corr_v2).
// ============================================================
__global__ void max_kernel(const float* __restrict__ corr, unsigned* __restrict__ gmax){
    float v = corr[(size_t)blockIdx.x * 256 + threadIdx.x];
    #pragma unroll
    for (int o = 32; o > 0; o >>= 1) v = fmaxf(v, __shfl_down(v, o));
    if ((threadIdx.x & 63) == 0) atomicMax(gmax, f2o(v));
}

// ============================================================
// att: softmax over the 25 offsets, in-place on corr buffer.
// ============================================================
__global__ void att_kernel(float* __restrict__ corr, const unsigned* __restrict__ gmax,
                           int logHW){
    const int p = blockIdx.x * 256 + threadIdx.x;
    const int b = p >> logHW;
    const int rem = p & ((1 << logHW) - 1);
    float* cp = corr + (((size_t)b * 25) << logHW) + rem;
    const float scale = 20.f / o2f(*gmax);

    float z[25]; float m = -INFINITY;
    #pragma unroll
    for (int k = 0; k < 25; k++){
        z[k] = cp[k << logHW] * scale;
        m = fmaxf(m, z[k]);
    }
    float s = 0.f;
    #pragma unroll
    for (int k = 0; k < 25; k++){ z[k] = expf(z[k] - m); s += z[k]; }
    const float inv = 1.f / s;
    #pragma unroll
    for (int k = 0; k < 25; k++) cp[k << logHW] = z[k] * inv;
}

// ============================================================
// warp v2 (verified r5)
// ============================================================
__global__ __launch_bounds__(256)
void warp_v2(const float* __restrict__ frame, const float* __restrict__ att,
             float* __restrict__ newf,
             int C, int CW, int H, int W, int logHW, int logW){
    const int tid = threadIdx.x, lane = tid & 63, wv = tid >> 6;
    const int HW = 1 << logHW;
    const int p0 = blockIdx.x * 64;
    const int b  = p0 >> logHW;
    const int remL = (p0 & (HW - 1)) + lane;
    const int y = remL >> logW, x = remL & (W - 1);

    int adr[4];
    const int dxs[4] = {-2, -1, 1, 2};
    #pragma unroll
    for (int i = 0; i < 4; i++) adr[i] = ((lane + dxs[i]) & 63) << 2;

    int roff[5];
    #pragma unroll
    for (int r = 0; r < 5; r++){
        const int dy = r - 2;
        roff[r] = ((unsigned)(y + dy) < (unsigned)H) ? dy * W : 0;
    }

    const float* ap = att + (((size_t)b * 25) << logHW) + remL;
    float a[25];
    #pragma unroll
    for (int t = 0; t < 25; t++){
        const int dy = t / 5 - 2, dx = t % 5 - 2;
        const float mk = (((unsigned)(y + dy) < (unsigned)H) &&
                          ((unsigned)(x + dx) < (unsigned)W)) ? 1.f : 0.f;
        a[t] = ap[(size_t)t << logHW] * mk;
    }

    const int c0 = (blockIdx.y * 4 + wv) * CW;
    const float* fp = frame + (((size_t)b * C + c0) << logHW) + remL;
    float*       op = newf  + (((size_t)b * C + c0) << logHW) + remL;

    for (int ci = 0; ci < CW; ci++){
        float f[5];
        #pragma unroll
        for (int r = 0; r < 5; r++) f[r] = fp[roff[r]];
        float acc = 0.f;
        #pragma unroll
        for (int r = 0; r < 5; r++){
            float v[5];
            v[0] = bperm(adr[0], f[r]);
            v[1] = bperm(adr[1], f[r]);
            v[2] = f[r];
            v[3] = bperm(adr[2], f[r]);
            v[4] = bperm(adr[3], f[r]);
            #pragma unroll
            for (int j = 0; j < 5; j++)
                acc += a[r * 5 + j] * v[j];
        }
        op[0] = acc;
        fp += HW; op += HW;
    }
}

// ============================================================
// gate v2 (verified r5)
// ============================================================
__global__ __launch_bounds__(256)
void gate_v2(const float* __restrict__ key, const float* __restrict__ newf,
             const float* __restrict__ Wg, float* __restrict__ gz,
             int C, int CW, int H, int W, int logHW, int logW){
    const int tid = threadIdx.x, lane = tid & 63, wv = tid >> 6;
    const int HW = 1 << logHW;
    const int p0 = blockIdx.x * 64;
    const int b  = p0 >> logHW;
    const int remL = (p0 & (HW - 1)) + lane;
    const int y = remL >> logW, x = remL & (W - 1);

    float m[9];
    #pragma unroll
    for (int t = 0; t < 9; t++){
        const int dy = t / 3 - 1, dx = t % 3 - 1;
        m[t] = (((unsigned)(y + dy) < (unsigned)H) &&
                ((unsigned)(x + dx) < (unsigned)W)) ? 1.f : 0.f;
    }
    const int adrL = ((lane - 1) & 63) << 2;
    const int adrR = ((lane + 1) & 63) << 2;

    int roff[3];
    #pragma unroll
    for (int r = 0; r < 3; r++){
        const int dy = r - 1;
        roff[r] = ((unsigned)(y + dy) < (unsigned)H) ? dy * W : 0;
    }

    const int c0 = (blockIdx.y * 4 + wv) * CW;   // u in [0, 2C); chunk never straddles C
    const float* base = (c0 < C)
        ? key  + (((size_t)b * C + c0)       << logHW)
        : newf + (((size_t)b * C + (c0 - C)) << logHW);
    const float* ip = base + remL;

    float z0 = 0.f, z1 = 0.f;
    for (int ci = 0; ci < CW; ci++){
        const int u = c0 + ci;
        const float* w0 = Wg + (size_t)u * 9;
        const float* w1 = Wg + ((size_t)2 * C + u) * 9;
        float f[3];
        #pragma unroll
        for (int r = 0; r < 3; r++) f[r] = ip[roff[r]];
        #pragma unroll
        for (int r = 0; r < 3; r++){
            float v[3];
            v[0] = bperm(adrL, f[r]);
            v[1] = f[r];
            v[2] = bperm(adrR, f[r]);
            #pragma unroll
            for (int j = 0; j < 3; j++){
                const float val = v[j] * m[r * 3 + j];
                z0 += val * w0[r * 3 + j];
                z1 += val * w1[r * 3 + j];
            }
        }
        ip += HW;
    }

    __shared__ float sz[2][4][64];
    sz[0][wv][lane] = z0; sz[1][wv][lane] = z1;
    __syncthreads();
    if (wv < 2){
        const float s = sz[wv][0][lane] + sz[wv][1][lane] +
                        sz[wv][2][lane] + sz[wv][3][lane];
        atomicAdd(gz + ((size_t)b * 2 + wv) * HW + remL, s);
    }
}

// ============================================================
// prep_gin: NCHW fp32 (key,new) * sigmoid(gz+bg) -> NHWC bf16 gin
// ============================================================
__global__ void prep_gin(const float* __restrict__ key, const float* __restrict__ newf,
                         const float* __restrict__ g, const float* __restrict__ bg,
                         unsigned short* __restrict__ gin,
                         int C, int HW){
    __shared__ unsigned short tile[64][65];
    int tid = threadIdx.x;
    int pt0 = blockIdx.x * 64;
    int u0  = blockIdx.y * 64;
    int b   = pt0 / HW;
    int rem0 = pt0 - b * HW;
    const float* gb = g + (size_t)(b * 2) * HW;

    #pragma unroll
    for (int it = 0; it < 16; it++){
        int idx = it * 256 + tid;
        int ur = idx >> 6, pc = idx & 63;
        int u = u0 + ur; int rem = rem0 + pc;
        const float* src; int sel;
        if (u < C){ src = key  + ((size_t)b * C + u) * HW;       sel = 0; }
        else      { src = newf + ((size_t)b * C + (u - C)) * HW; sel = 1; }
        float zz = gb[(size_t)sel * HW + rem] + bg[sel];
        float gv = 1.f / (1.f + expf(-zz));
        float v = src[rem] * gv;
        tile[ur][pc] = f2bf(v);
    }
    __syncthreads();
    unsigned short* go = gin + (size_t)pt0 * (2 * C) + u0;
    #pragma unroll
    for (int it = 0; it < 16; it++){
        int idx = it * 256 + tid;
        int pr = idx >> 6, uc = idx & 63;
        go[(size_t)pr * (2 * C) + uc] = tile[uc][pr];
    }
}

// ============================================================
// prep_w: W[co][ci][t] fp32 -> Wt[co][t*Cin+ci] bf16
// ============================================================
__global__ void prep_w(const float* __restrict__ W, unsigned short* __restrict__ Wt,
                       int Cin){
    int ci = blockIdx.y * 256 + threadIdx.x;
    int bx = blockIdx.x;
    int co = bx / 9, t = bx - co * 9;
    Wt[(size_t)bx * Cin + ci] = f2bf(W[((size_t)co * Cin + ci) * 9 + t]);
}

// ============================================================
// conv_mfma v6: PAIR-STEP reg-staged pipeline. v5 (reg-staged,
// 1 K-block/barrier) hit 149us with MfmaUtil 15.6% — the ~72%
// stall is the per-barrier serial chain paid 144x. Now 2 K-blocks
// per barrier: 4 LDS buffers (2 sets x 2 subs), 2 pairs of loads
// in flight (counted vmcnt(6)/vmcnt(4)), one lgkmcnt(0)+s_barrier
// per pair, 16-MFMA cluster per barrier. npairs always even ->
// 2-pair unrolled loop, named reg sets R0..R3 (static indexing).
// ============================================================
template<int BN, int EPI>
__global__ __launch_bounds__(256, 2)
void conv_mfma(const unsigned short* __restrict__ gin,
               const unsigned short* __restrict__ Wt,
               const float* __restrict__ bias,
               unsigned short* __restrict__ obf, int ostride,
               float* __restrict__ of32,
               const void* __restrict__ zp,
               int Cin, int Cout, int H, int W, int logHW, int logW)
{
    constexpr int BM = 64;
    constexpr int BNh = BN / 2;
    constexpr int NJ = BN / 32;
    __shared__ __align__(16) unsigned short sA[4][BM * 32];
    __shared__ __align__(16) unsigned short sB[4][BN * 32];

    const int tid = threadIdx.x;
    const int lane = tid & 63;
    const int wv = tid >> 6;
    const int wm = wv >> 1, wn = wv & 1;
    const int ln = lane & 15, q = lane >> 4;

    const int p0 = blockIdx.x * BM;
    const int b  = p0 >> logHW;
    const int rem0 = p0 - (b << logHW);

    // staging: row = tid>>2 (0..63); swizzled global chunk
    const int rowA0 = tid >> 2;
    const int gc8 = ((tid & 3) ^ ((tid >> 3) & 3)) * 8;    // element offset
    const int remA0 = rem0 + rowA0;
    const int yA0 = remA0 >> logW, xA0 = remA0 & (W - 1);
    const size_t pbase = ((size_t)b << logHW);

    const int nt0 = blockIdx.y * BN;
    const size_t Ktot = (size_t)9 * Cin;
    const unsigned short* wB0 = Wt + (size_t)(nt0 + rowA0) * Ktot + gc8;

    f4v acc[2][NJ];
    #pragma unroll
    for (int i = 0; i < 2; i++)
        #pragma unroll
        for (int j = 0; j < NJ; j++){ f4v z = {0.f, 0.f, 0.f, 0.f}; acc[i][j] = z; }

    const int cblocks = Cin >> 5;
    const int total = 9 * cblocks;       // 144/216/288/432 — always even
    const int npairs = total >> 1;       // 72/108/144/216 — always even

    // staging-cursor state (for the NEXT K-block to issue)
    int scb = 0;                                   // k-chunk within tap
    int st  = 0;                                   // tap index
    bool sv = (yA0 > 0) && (xA0 > 0);              // tap 0: dy=-1,dx=-1
    const unsigned short* sa  = gin + (pbase + remA0 + (-W - 1)) * Cin + gc8;
    const unsigned short* swb = wB0;               // +32 per issued K-block

    struct Regs { f4v a, b0, b1; };
    Regs R0, R1, R2, R3;

    auto issue1 = [&](Regs& r){
        r.a  = *(const f4v*)(sv ? (const void*)(sa + scb * 32) : zp);
        r.b0 = *(const f4v*)swb;
        if constexpr (BN == 128) r.b1 = *(const f4v*)(swb + (size_t)64 * Ktot);
        swb += 32;
        if (++scb == cblocks){
            scb = 0; ++st;
            const int dy = st / 3 - 1, dx = st - (st / 3) * 3 - 1;
            sv = ((unsigned)(yA0 + dy) < (unsigned)H) && ((unsigned)(xA0 + dx) < (unsigned)W);
            sa = gin + (pbase + remA0 + dy * W + dx) * Cin + gc8;
        }
    };
    auto commit1 = [&](const Regs& r, int buf){
        *(f4v*)((char*)sA[buf] + (size_t)tid * 16) = r.a;
        char* dB = (char*)sB[buf];
        *(f4v*)(dB + (size_t)tid * 16) = r.b0;
        if constexpr (BN == 128) *(f4v*)(dB + 4096 + (size_t)tid * 16) = r.b1;
    };

    const int rchunk = (q ^ ((ln >> 1) & 3)) * 8;   // swizzled read offset
    auto compute1 = [&](int buf){
        const unsigned short* A = sA[buf];
        const unsigned short* B = sB[buf];
        s8v af[2];
        #pragma unroll
        for (int i = 0; i < 2; i++)
            af[i] = *(const s8v*)(A + (wm * 32 + i * 16 + ln) * 32 + rchunk);
        __builtin_amdgcn_s_setprio(1);
        #pragma unroll
        for (int j = 0; j < NJ; j++){
            s8v bfr = *(const s8v*)(B + (wn * BNh + j * 16 + ln) * 32 + rchunk);
            #pragma unroll
            for (int i = 0; i < 2; i++)
                acc[i][j] = mfma16(af[i], bfr, acc[i][j]);
        }
        __builtin_amdgcn_s_setprio(0);
    };

    // vmcnt literal = loads per PAIR still in flight (BN==128 -> 6, else 4)
    #define WAIT_CUR()  do{ if constexpr (BN == 128) asm volatile("s_waitcnt vmcnt(6)" ::: "memory"); \
                            else                     asm volatile("s_waitcnt vmcnt(4)" ::: "memory"); }while(0)
    #define WAIT_ALL()  asm volatile("s_waitcnt vmcnt(0)" ::: "memory")

    // prologue: pairs 0 and 1 in flight
    issue1(R0); issue1(R1); issue1(R2); issue1(R3);

    for (int t = 0; t < npairs; t += 2){
        // ---- pair t: regs R0,R1 -> bufs 0,1 ----
        if (t + 1 < npairs) WAIT_CUR(); else WAIT_ALL();
        __builtin_amdgcn_sched_barrier(0);
        commit1(R0, 0); commit1(R1, 1);
        if (t + 2 < npairs){ issue1(R0); issue1(R1); }   // pair t+2
        asm volatile("s_waitcnt lgkmcnt(0)" ::: "memory");
        __builtin_amdgcn_sched_barrier(0);
        __builtin_amdgcn_s_barrier();
        compute1(0); compute1(1);

        // ---- pair t+1: regs R2,R3 -> bufs 2,3 ----
        if (t + 2 < npairs) WAIT_CUR(); else WAIT_ALL();
        __builtin_amdgcn_sched_barrier(0);
        commit1(R2, 2); commit1(R3, 3);
        if (t + 3 < npairs){ issue1(R2); issue1(R3); }   // pair t+3
        asm volatile("s_waitcnt lgkmcnt(0)" ::: "memory");
        __builtin_amdgcn_sched_barrier(0);
        __builtin_amdgcn_s_barrier();
        compute1(2); compute1(3);
    }
    #undef WAIT_CUR
    #undef WAIT_ALL

    // epilogue: D rows m = q*4+r (pixels), cols n = ln (cout)
    #pragma unroll
    for (int i = 0; i < 2; i++){
        const int m0 = wm * 32 + i * 16 + q * 4;
        const int p = p0 + m0;
        #pragma unroll
        for (int j = 0; j < NJ; j++){
            const int n = nt0 + wn * BNh + j * 16 + ln;
            const float bv = bias[n];
            if (EPI == 0){
                #pragma unroll
                for (int r = 0; r < 4; r++){
                    float v = fmaxf(acc[i][j][r] + bv, 0.f);
                    obf[(size_t)(p + r) * ostride + n] = f2bf(v);
                }
            } else {
                f4v o;
                #pragma unroll
                for (int r = 0; r < 4; r++) o[r] = fmaxf(acc[i][j][r] + bv, 0.f);
                const int rem = rem0 + m0;
                *(f4v*)(of32 + (((size_t)b * Cout + n) << logHW) + rem) = o;
            }
        }
    }
}

// ============================================================
extern "C" void kernel_launch(void* const* d_in, const int* in_sizes, int n_in,
                              void* d_out, int out_size, void* d_ws, size_t ws_size,
                              hipStream_t stream){
    (void)in_sizes; (void)n_in; (void)out_size; (void)ws_size;

    const float* X[4][2];
    for (int s = 0; s < 4; s++)
        for (int l = 0; l < 2; l++)
            X[s][l] = (const float*)d_in[s * 2 + l];
    const float* Wg[2] = { (const float*)d_in[8],  (const float*)d_in[14] };
    const float* bg[2] = { (const float*)d_in[9],  (const float*)d_in[15] };
    const float* Wd[2] = { (const float*)d_in[10], (const float*)d_in[16] };
    const float* bd[2] = { (const float*)d_in[11], (const float*)d_in[17] };
    const float* Wc[2] = { (const float*)d_in[12], (const float*)d_in[18] };
    const float* bc[2] = { (const float*)d_in[13], (const float*)d_in[19] };
    float* out = (float*)d_out;

    char* ws = (char*)d_ws;
    unsigned* gmax = (unsigned*)ws;
    const void* zp = (const void*)(ws + 1024);
    float* corrbuf = (float*)(ws + 4096);
    float* newbuf  = (float*)(ws + 4096 + 1638400);
    unsigned short* wtbuf = (unsigned short*)newbuf;   // alias, disjoint lifetime
    float* gbuf    = (float*)(ws + 4096 + 1638400 + 16777216);
    unsigned short* ginbuf = (unsigned short*)(ws + 4096 + 1638400 + 16777216 + 131072);
    unsigned short* totbuf = (unsigned short*)(ws + 4096 + 1638400 + 16777216 + 131072 + 16777216);

    hipMemsetAsync(ws, 0, 4096, stream);

    const int Cs[2] = {256, 512};
    const int Hs[2] = {64, 32};
    const int logWs[2] = {6, 5};
    const int logHWs[2] = {12, 10};
    const size_t outOff[2] = {0, (size_t)4 * 256 * 4096};

    for (int l = 0; l < 2; l++){
        const int C = Cs[l], H = Hs[l], W = Hs[l], HW = H * W;
        const int logW = logWs[l], logHW = logHWs[l];
        const float* key = X[3][l];
        const int pblk = 4 * HW / 256;
        const int Mt = 4 * HW / 64;            // BM=64 tiles

        const int gx  = 4 * HW / 64;           // row-band tiles: {256, 64}
        const int S   = (l == 0) ? 2 : 8;      // c-split across grid.y -> 512 blocks
        const int CWc = C / (4 * S);           // channels per wave (corr/warp)
        const int CWg = (2 * C) / (4 * S);     // channels per wave (gate)

        for (int s = 0; s < 3; s++){
            const float* fr = X[s][l];
            unsigned* slot = gmax + (l * 3 + s);
            hipMemsetAsync(corrbuf, 0, (size_t)4 * 25 * HW * 4, stream);
            hipMemsetAsync(gbuf,    0, (size_t)4 * 2 * HW * 4, stream);
            corr_v2<<<dim3(gx, S), 256, 0, stream>>>(
                key, fr, corrbuf, C, CWc, H, W, logHW, logW);
            max_kernel<<<25 * 4 * HW / 256, 256, 0, stream>>>(corrbuf, slot);
            att_kernel<<<pblk, 256, 0, stream>>>(corrbuf, slot, logHW);
            warp_v2<<<dim3(gx, S), 256, 0, stream>>>(
                fr, corrbuf, newbuf, C, CWc, H, W, logHW, logW);
            gate_v2<<<dim3(gx, S), 256, 0, stream>>>(
                key, newbuf, Wg[l] + (size_t)s * 2 * (2 * C) * 9,
                gbuf, C, CWg, H, W, logHW, logW);
            prep_gin<<<dim3(4 * HW / 64, 2 * C / 64), 256, 0, stream>>>(
                key, newbuf, gbuf, bg[l] + (size_t)s * 2, ginbuf, C, HW);
            prep_w<<<dim3(C * 9, 2 * C / 256), 256, 0, stream>>>(
                Wd[l] + (size_t)s * C * 2 * C * 9, wtbuf, 2 * C);
            if (l == 0)
                conv_mfma<128, 0><<<dim3(Mt, C / 128), 256, 0, stream>>>(
                    ginbuf, wtbuf, bd[l] + s * C, totbuf + s * C, 3 * C,
                    nullptr, zp, 2 * C, C, H, W, logHW, logW);
            else
                conv_mfma<64, 0><<<dim3(Mt, C / 64), 256, 0, stream>>>(
                    ginbuf, wtbuf, bd[l] + s * C, totbuf + s * C, 3 * C,
                    nullptr, zp, 2 * C, C, H, W, logHW, logW);
        }
        prep_w<<<dim3(C * 9, 3 * C / 256), 256, 0, stream>>>(Wc[l], wtbuf, 3 * C);
        if (l == 0)
            conv_mfma<128, 1><<<dim3(Mt, 2), 256, 0, stream>>>(
                totbuf, wtbuf, bc[l], nullptr, 0,
                out + outOff[l], zp, 3 * C, C, H, W, logHW, logW);
        else
            conv_mfma<64, 1><<<dim3(Mt, 8), 256, 0, stream>>>(
                totbuf, wtbuf, bc[l], nullptr, 0,
                out + outOff[l], zp, 3 * C, C, H, W, logHW, logW);
    }
}